// Round 3
// baseline (485.212 us; speedup 1.0000x reference)
//
#include <hip/hip_runtime.h>

typedef __attribute__((ext_vector_type(4))) float f4;
typedef __attribute__((ext_vector_type(8))) short s8;

__device__ __forceinline__ unsigned short f2bf(float x){
  unsigned u = __float_as_uint(x);
  u += 0x7fffu + ((u >> 16) & 1u);
  return (unsigned short)(u >> 16);
}
__device__ __forceinline__ float lrelu(float v){ return v > 0.f ? v : 0.2f * v; }

__device__ __forceinline__ void gload16(const unsigned short* g, unsigned short* l){
  __builtin_amdgcn_global_load_lds((const __attribute__((address_space(1))) unsigned int*)g,
                                   (__attribute__((address_space(3))) unsigned int*)l, 16, 0, 0);
}

// ---------------- prep 1: zero accumulators + p/q = W @ a_src / a_dst ----------------
__global__ void prep_pq(const float* __restrict__ Wg, const float* __restrict__ a_src,
                        const float* __restrict__ a_dst, float* __restrict__ pq,
                        float* __restrict__ zbase){
  int tid = blockIdx.x * 256 + threadIdx.x;
  for (int i = tid; i < 18444; i += gridDim.x * 256) zbase[i] = 0.f;  // Craw3,Craw1,den,HE2,HE0,B,C
  int wid = tid >> 6, lane = tid & 63;
  for (int task = wid; task < 4096; task += gridDim.x * 4){
    int g = task >> 10, isq = (task >> 9) & 1, r = task & 511;
    const float* w = Wg + ((g * 512 + r) << 9);
    const float* a = (isq ? a_dst : a_src) + g * 512;
    float s = 0.f;
    for (int i = lane; i < 512; i += 64) s += w[i] * a[i];
    for (int off = 32; off; off >>= 1) s += __shfl_down(s, off);
    if (lane == 0) pq[task] = s;
  }
}

// ---------------- prep 2: W2^T, W0^T as bf16 (n-major, contiguous k) ----------------
__global__ void prep_wt(const float* __restrict__ Wg, unsigned short* __restrict__ W2T,
                        unsigned short* __restrict__ W0T){
  __shared__ float tile[32][33];
  const int b = blockIdx.x;
  const int m = b >> 8;                      // 0: W2 -> W2T, 1: W0 -> W0T
  const int kb = (b & 15) * 32;
  const int nb = ((b >> 4) & 15) * 32;
  const float* W = Wg + (m == 0 ? 2 * 262144 : 0);
  unsigned short* WT = (m == 0) ? W2T : W0T;
  const int tx = threadIdx.x & 31, ty = threadIdx.x >> 5;
  #pragma unroll
  for (int i = 0; i < 32; i += 8) tile[ty + i][tx] = W[(kb + ty + i) * 512 + nb + tx];
  __syncthreads();
  #pragma unroll
  for (int i = 0; i < 32; i += 8) WT[(nb + ty + i) * 512 + kb + tx] = f2bf(tile[tx][ty + i]);
}

// ---------------- prep: 48 exercise scalar dots: asE/adE[g][e] = exer_e . pq[g][s/d] ----------------
__global__ void prep_scal(const float* __restrict__ exer, const float* __restrict__ pq,
                          float* __restrict__ asE, float* __restrict__ adE){
  const int t = threadIdx.x, wid = t >> 6, lane = t & 63;
  for (int task = wid; task < 48; task += 4){
    int gg = task / 12, rem = task % 12, isq = rem / 6, e = rem % 6;
    const float* X = exer + e * 512;
    const float* V = pq + gg * 1024 + isq * 512;
    float s = 0.f;
    for (int i = lane; i < 512; i += 64) s += X[i] * V[i];
    for (int off = 32; off; off >>= 1) s += __shfl_down(s, off);
    if (lane == 0) (isq ? adE : asE)[gg * 6 + e] = s;
  }
}

// ---------------- prep 3 (split-k): HE_g[e] += exer_e[kslice] @ W_g[kslice] ----------------
__global__ void prep_he(const float* __restrict__ exer, const float* __restrict__ Wg,
                        float* __restrict__ HE2, float* __restrict__ HE0){
  const int b = blockIdx.x;           // 0..11
  const int ks = blockIdx.y;          // 0..7
  const int g = (b < 6) ? 0 : 2;
  const int e = b % 6;
  __shared__ float xs[64];
  const int t = threadIdx.x;          // 512
  if (t < 64) xs[t] = exer[e * 512 + ks * 64 + t];
  __syncthreads();
  const float* W = Wg + g * 262144 + ks * 64 * 512;
  float acc = 0.f;
  #pragma unroll 4
  for (int kk = 0; kk < 64; kk++) acc += xs[kk] * W[kk * 512 + t];
  atomicAdd(&((g == 0) ? HE0 : HE2)[e * 512 + t], acc);
}

// ---------------- pass 1: per-row scalars (receive softmax) + send-side accumulation ----------------
template<int DEG>
__launch_bounds__(256)
__global__ void pass1(const float* __restrict__ x, const float* __restrict__ pq,
                      int gA, int gB,
                      const float* __restrict__ asE, const float* __restrict__ adE,
                      float* __restrict__ alph, const int* __restrict__ idx,
                      float* __restrict__ Craw, float* __restrict__ den, int M)
{
  __shared__ float sC[3072];
  __shared__ float sDen[6];
  const int tid = threadIdx.x, lane = tid & 63, wid = tid >> 6;
  for (int i = tid; i < 3072; i += 256) sC[i] = 0.f;
  if (tid < 6) sDen[tid] = 0.f;

  const int kb = lane * 8;
  const float* pqA = pq + gA * 1024;
  const float* pqB = pq + gB * 1024;
  f4 pA0 = *(const f4*)(pqA + kb),       pA1 = *(const f4*)(pqA + kb + 4);
  f4 qA0 = *(const f4*)(pqA + 512 + kb), qA1 = *(const f4*)(pqA + 512 + kb + 4);
  f4 pB0 = *(const f4*)(pqB + kb),       pB1 = *(const f4*)(pqB + kb + 4);
  float aseR = asE[gA * 6 + (lane % 6)];
  float adeR = adE[gB * 6 + (lane % 6)];

  float cacc[6][8];
  #pragma unroll
  for (int e = 0; e < 6; e++)
    #pragma unroll
    for (int i = 0; i < 8; i++) cacc[e][i] = 0.f;
  float dacc[6] = {0.f,0.f,0.f,0.f,0.f,0.f};
  __syncthreads();

  const int gw = blockIdx.x * 4 + wid, nw = gridDim.x * 4;
  for (int r = gw; r < M; r += nw){
    const float* xr = x + (size_t)r * 512;
    f4 x0 = *(const f4*)(xr + kb), x1 = *(const f4*)(xr + kb + 4);
    float dP = 0.f, dQ = 0.f, dB = 0.f;
    #pragma unroll
    for (int i = 0; i < 4; i++){
      dP += x0[i]*pA0[i] + x1[i]*pA1[i];
      dQ += x0[i]*qA0[i] + x1[i]*qA1[i];
      dB += x0[i]*pB0[i] + x1[i]*pB1[i];
    }
    #pragma unroll
    for (int off = 1; off < 64; off <<= 1){
      dP += __shfl_xor(dP, off); dQ += __shfl_xor(dQ, off); dB += __shfl_xor(dB, off);
    }
    int ei[DEG];
    #pragma unroll
    for (int j = 0; j < DEG; j++) ei[j] = idx[r * DEG + j];
    float scS = lrelu(dP + dQ);
    float sc[DEG], m = scS;
    #pragma unroll
    for (int j = 0; j < DEG; j++){ sc[j] = lrelu(__shfl(aseR, ei[j]) + dQ); m = fmaxf(m, sc[j]); }
    float eS = __expf(scS - m), sum = eS;
    float ev[DEG];
    #pragma unroll
    for (int j = 0; j < DEG; j++){ ev[j] = __expf(sc[j] - m); sum += ev[j]; }
    float inv = 1.f / sum;
    // write [alpha_self, coef0..5, 0]
    float val = 0.f;
    if (lane == 0) val = eS * inv;
    else if (lane < 7){
      #pragma unroll
      for (int j = 0; j < DEG; j++) val += (ei[j] == lane - 1) ? ev[j] * inv : 0.f;
    }
    if (lane < 8) alph[(size_t)r * 8 + lane] = val;
    // send-side weights
    float wj[DEG];
    #pragma unroll
    for (int j = 0; j < DEG; j++) wj[j] = __expf(lrelu(dB + __shfl(adeR, ei[j])));
    #pragma unroll
    for (int e = 0; e < 6; e++){
      float we = 0.f;
      #pragma unroll
      for (int j = 0; j < DEG; j++) we += (ei[j] == e) ? wj[j] : 0.f;
      dacc[e] += we;
      #pragma unroll
      for (int i = 0; i < 4; i++){ cacc[e][i] += we * x0[i]; cacc[e][4+i] += we * x1[i]; }
    }
  }
  // block-level reduction
  #pragma unroll
  for (int e = 0; e < 6; e++)
    #pragma unroll
    for (int i = 0; i < 8; i++)
      atomicAdd(&sC[e * 512 + kb + i], cacc[e][i]);
  if (lane == 0){
    #pragma unroll
    for (int e = 0; e < 6; e++) atomicAdd(&sDen[e], dacc[e]);
  }
  __syncthreads();
  for (int i = tid; i < 3072; i += 256){
    float v = sC[i];
    if (v != 0.f) atomicAdd(&Craw[i], v);
  }
  if (tid < 6) atomicAdd(&den[tid], sDen[tid]);
}

// ---------------- pass 2: barrier-free GEMM + fused GAT epilogue ----------------
// Block: 512 thr (8 waves), BM=128 (16 rows/wave), BN=64.  B panel (64x512 bf16,
// XOR-swizzled) staged in LDS once; A fragments read per-wave from global.
__launch_bounds__(512, 4)
__global__ void gemm_ep(const float* __restrict__ x, const unsigned short* __restrict__ WT,
                        const float* __restrict__ alph, const float* __restrict__ HE,
                        const float* __restrict__ bA, float* __restrict__ outp, int M)
{
  __shared__ __align__(16) unsigned short sB[32768];   // [64 rows][64 slots of 8 ush], slot^=(row&7)
  __shared__ __align__(16) float sAl[1024];
  __shared__ __align__(16) float sHEb[384];
  __shared__ __align__(16) float sBias[64];

  // bijective XCD chunking: contiguous mb-range per XCD, nb fastest
  const int nwg = gridDim.x;                 // multiple of 8
  const int xcd = blockIdx.x & 7, pos = blockIdx.x >> 3;
  const int wido = xcd * (nwg >> 3) + pos;
  const int mb = wido >> 3, nb = wido & 7;
  const int r0 = mb * 128, n0 = nb * 64;
  const int tid = threadIdx.x, lane = tid & 63, w = tid >> 6;
  const int l16 = lane & 15, lhi = lane >> 4;

  // stage B (swizzled source, linear LDS dest)
  {
    const int row = (tid >> 6), slot = tid & 63;
    #pragma unroll
    for (int it = 0; it < 8; it++){
      const int rr = it * 8 + row;
      const unsigned short* src = WT + (size_t)(n0 + rr) * 512 + ((slot ^ (rr & 7)) << 3);
      gload16(src, sB + it * 4096 + tid * 8);
    }
  }
  if (tid < 256){
    const int row = tid >> 1;
    *(f4*)(sAl + tid * 4) = *(const f4*)(alph + (size_t)min(r0 + row, M - 1) * 8 + (tid & 1) * 4);
  } else if (tid < 352){
    const int idx2 = tid - 256, e = idx2 >> 4, c4 = idx2 & 15;
    *(f4*)(sHEb + e * 64 + c4 * 4) = *(const f4*)(HE + e * 512 + n0 + c4 * 4);
  } else if (tid < 368){
    const int idx2 = tid - 352;
    *(f4*)(sBias + idx2 * 4) = *(const f4*)(bA + n0 + idx2 * 4);
  }
  __syncthreads();

  const int gr0 = r0 + w * 16 + l16;
  const float* xr = x + (size_t)min(gr0, M - 1) * 512 + lhi * 8;

  f4 acc[4];
  #pragma unroll
  for (int n = 0; n < 4; n++) acc[n] = (f4){0.f, 0.f, 0.f, 0.f};

  #pragma unroll 4
  for (int kt = 0; kt < 16; kt++){
    f4 a0 = *(const f4*)(xr + kt * 32);
    f4 a1 = *(const f4*)(xr + kt * 32 + 4);
    s8 af;
    #pragma unroll
    for (int i = 0; i < 4; i++){ af[i] = (short)f2bf(a0[i]); af[4+i] = (short)f2bf(a1[i]); }
    #pragma unroll
    for (int n = 0; n < 4; n++){
      const int row = n * 16 + l16;
      const int slot = ((kt << 2) + lhi) ^ (row & 7);
      s8 bf = *(const s8*)(sB + row * 512 + (slot << 3));
      acc[n] = __builtin_amdgcn_mfma_f32_16x16x32_bf16(af, bf, acc[n], 0, 0, 0);
    }
  }

  // preload per-lane HE columns + bias
  float hec[4][6], bias[4];
  #pragma unroll
  for (int n = 0; n < 4; n++){
    bias[n] = sBias[n * 16 + l16];
    #pragma unroll
    for (int e = 0; e < 6; e++) hec[n][e] = sHEb[e * 64 + n * 16 + l16];
  }

  // epilogue: out = x + a_self*(x@W) + sum_e coef_e*HE[e] + b
  #pragma unroll
  for (int j = 0; j < 4; j++){
    const int rl = w * 16 + lhi * 4 + j;
    const int gr = r0 + rl;
    if (gr < M){
      f4 alA = *(const f4*)(sAl + rl * 8);
      f4 alB = *(const f4*)(sAl + rl * 8 + 4);
      const float aself = alA[0];
      #pragma unroll
      for (int n = 0; n < 4; n++){
        const int gc = n0 + n * 16 + l16;
        float v = x[(size_t)gr * 512 + gc] + aself * acc[n][j] + bias[n];
        v += alA[1] * hec[n][0] + alA[2] * hec[n][1] + alA[3] * hec[n][2];
        v += alB[0] * hec[n][3] + alB[1] * hec[n][4] + alB[2] * hec[n][5];
        outp[(size_t)gr * 512 + gc] = v;
      }
    }
  }
}

// ---------------- finalize B (GAT1) and C (GAT3), split-k ----------------
__global__ void finalize_bc(const float* __restrict__ exer, const float* __restrict__ Wg,
                            const float* __restrict__ asE, const float* __restrict__ adE,
                            const float* __restrict__ Craw3, const float* __restrict__ den3,
                            const float* __restrict__ Craw1, const float* __restrict__ den1,
                            const float* __restrict__ b_gat, float* __restrict__ B,
                            float* __restrict__ C){
  const int b = blockIdx.x;          // 0..11
  const int ks = blockIdx.y;         // 0..7
  const int isC = (b >= 6) ? 1 : 0;
  const int e = b % 6;
  const int g = isC ? 3 : 1;
  const float* Craw = isC ? Craw3 : Craw1;
  const float* den  = isC ? den3  : den1;
  __shared__ float mix[64];
  const int t = threadIdx.x;          // 512
  float aS = asE[g*6 + e], aD = adE[g*6 + e];
  float wself = __expf(lrelu(aS + aD));
  float dn = den[e] + wself;
  if (t < 64){
    int k = ks * 64 + t;
    mix[t] = (Craw[e*512 + k] + wself * exer[e*512 + k]) / dn;
  }
  __syncthreads();
  const float* W = Wg + g * 262144 + ks * 64 * 512;
  float acc = 0.f;
  #pragma unroll 4
  for (int kk = 0; kk < 64; kk++) acc += mix[kk] * W[kk * 512 + t];
  if (ks == 0) acc += b_gat[g*512 + t];
  atomicAdd(&(isC ? C : B)[e*512 + t], acc);
}

// ---------------- final exercise attention + output ----------------
__global__ void finalize_exer(const float* __restrict__ exer, const float* __restrict__ B,
                              const float* __restrict__ C, const float* __restrict__ attn_w,
                              const float* __restrict__ attn_b, float* __restrict__ outE){
  __shared__ float s1[6], s2[6];
  const int t = threadIdx.x, wid = t >> 6, lane = t & 63;
  for (int task = wid; task < 12; task += 8){
    int e = task >> 1, which = task & 1;
    const float* w = attn_w + (which + 1) * 1024;
    const float* X = exer + e * 512;
    const float* Y = (which ? C : B) + e * 512;
    float s = 0.f;
    for (int i = lane; i < 512; i += 64) s += X[i] * w[i] + Y[i] * w[512 + i];
    for (int off = 32; off; off >>= 1) s += __shfl_down(s, off);
    if (lane == 0) (which ? s2 : s1)[e] = s + attn_b[which + 1];
  }
  __syncthreads();
  for (int i = t; i < 3072; i += 512){
    int e = i >> 9;
    float a = s1[e], b = s2[e];
    float m = fmaxf(a, b);
    float ea = __expf(a - m), eb = __expf(b - m);
    float inv = 1.f / (ea + eb);
    outE[i] = exer[i] + (ea * inv) * B[i] + (eb * inv) * C[i];
  }
}

extern "C" void kernel_launch(void* const* d_in, const int* in_sizes, int n_in,
                              void* d_out, int out_size, void* d_ws, size_t ws_size,
                              hipStream_t stream){
  const float* kn     = (const float*)d_in[0];
  const float* exer   = (const float*)d_in[1];
  const float* stu    = (const float*)d_in[2];
  const float* Wg     = (const float*)d_in[3];
  const float* a_src  = (const float*)d_in[4];
  const float* a_dst  = (const float*)d_in[5];
  const float* b_gat  = (const float*)d_in[6];
  const float* attn_w = (const float*)d_in[7];
  const float* attn_b = (const float*)d_in[8];
  const int*   e_ke   = (const int*)d_in[9];
  const int*   e_ue   = (const int*)d_in[11];
  float* out = (float*)d_out;

  unsigned short* W2T = (unsigned short*)d_ws;
  unsigned short* W0T = W2T + 262144;
  float* fb    = (float*)(W0T + 262144);
  float* pq    = fb;                 // 4096
  float* asE   = pq + 4096;          // 24
  float* adE   = asE + 24;           // 24
  float* Craw3 = adE + 24;           // 3072  -- zero region starts here
  float* Craw1 = Craw3 + 3072;       // 3072
  float* den3  = Craw1 + 3072;       // 6
  float* den1  = den3 + 6;           // 6
  float* HE2   = den1 + 6;           // 3072
  float* HE0   = HE2 + 3072;         // 3072
  float* Bb    = HE0 + 3072;         // 3072
  float* Cc    = Bb + 3072;          // 3072  -- zero region = 18444 floats
  float* alphS = Cc + 3072;          // 400384
  float* alphK = alphS + 400384;     // 4096

  hipLaunchKernelGGL(prep_pq, dim3(256), dim3(256), 0, stream, Wg, a_src, a_dst, pq, Craw3);
  hipLaunchKernelGGL(prep_wt, dim3(512), dim3(256), 0, stream, Wg, W2T, W0T);
  hipLaunchKernelGGL(prep_scal, dim3(1), dim3(256), 0, stream, exer, pq, asE, adE);
  hipLaunchKernelGGL(prep_he, dim3(12, 8), dim3(512), 0, stream, exer, Wg, HE2, HE0);

  // pass 1: students (receive GAT2, send GAT3) and knowledge (receive GAT0, send GAT1)
  hipLaunchKernelGGL((pass1<3>), dim3(768), dim3(256), 0, stream,
                     stu, pq, 2, 3, asE, adE, alphS, e_ue, Craw3, den3, 50000);
  hipLaunchKernelGGL((pass1<4>), dim3(8), dim3(256), 0, stream,
                     kn, pq, 0, 1, asE, adE, alphK, e_ke, Craw1, den1, 512);

  // pass 2: barrier-free fused GEMM + epilogue
  hipLaunchKernelGGL(gemm_ep, dim3(391 * 8), dim3(512), 0, stream,
                     stu, W2T, alphS, HE2, b_gat + 1024, out + 265216, 50000);
  hipLaunchKernelGGL(gemm_ep, dim3(4 * 8), dim3(512), 0, stream,
                     kn, W0T, alphK, HE0, b_gat, out, 512);

  hipLaunchKernelGGL(finalize_bc, dim3(12, 8), dim3(512), 0, stream,
                     exer, Wg, asE, adE, Craw3, den3, Craw1, den1, b_gat, Bb, Cc);
  hipLaunchKernelGGL(finalize_exer, dim3(1), dim3(512), 0, stream,
                     exer, Bb, Cc, attn_w, attn_b, out + 262144);
}